// Round 7
// baseline (2974.512 us; speedup 1.0000x reference)
//
#include <hip/hip_runtime.h>

#define TT     32
#define HW     4096           // 64*64
#define LROW   68             // 66 cols + 2 pad -> rows 16B-aligned (b128 reads)
#define LPLANE (6 * LROW)     // 6 halo rows per cin = 408
#define SXSZ   (3 * LPLANE)   // 1224 floats per plane buffer
#define NSTG   (3 * 6 * 66)   // 1188 staged elements per plane

__device__ __forceinline__ float fsigmoid(float x) {
    return __builtin_amdgcn_rcpf(1.0f + __builtin_amdgcn_exp2f(x * -1.4426950408889634f));
}
__device__ __forceinline__ float ftanh(float x) {
    return 2.0f * __builtin_amdgcn_rcpf(1.0f + __builtin_amdgcn_exp2f(x * -2.8853900817779268f)) - 1.0f;
}
// force a wave-uniform float into an SGPR
__device__ __forceinline__ float sgprf(float v) {
    return __uint_as_float(__builtin_amdgcn_readfirstlane(__float_as_uint(v)));
}

__global__ __launch_bounds__(256, 4) void convqrnn(
    const float* __restrict__ X,    // (4,3,32,64,64)
    const float* __restrict__ Wc,   // (256,3,2,3,3)
    const float* __restrict__ bc,   // (256)
    const float* __restrict__ Wci,  // (64,64,64)
    const float* __restrict__ Wcf,
    const float* __restrict__ Wco,
    float* __restrict__ out)        // (4,64,32,64,64)
{
    __shared__ float sx[2 * SXSZ];   // double-buffered staged plane (9792 B)
    __shared__ float wl[1152];       // weights: ((cl*4+g)*9 + ci*3+kh)*8 + dt*3 + kw

    const int tid = threadIdx.x;
    const int h0  = blockIdx.x * 4;    // 16 row-tiles of height 4, full width
    const int co0 = blockIdx.y * 4;    // this block handles couts co0..co0+3
    const int b   = blockIdx.z;

    // wave cl owns cout co0+cl, ALL 4 gates, for its lane's 4-col strip
    const int cl = tid >> 6;           // wave-uniform cout-local
    const int co = co0 + cl;
    const int l  = tid & 63;
    const int r  = l >> 4;             // 0..3 tile row
    const int c0 = (l & 15) * 4;       // col base (0,4,...,60)

    // peephole params for this thread's 4 pixels: contiguous -> float4
    const int pbase = co * HW + (h0 + r) * 64 + c0;
    float wciA[4], wcfA[4], wcoA[4];
    *(float4*)wciA = *(const float4*)&Wci[pbase];
    *(float4*)wcfA = *(const float4*)&Wcf[pbase];
    *(float4*)wcoA = *(const float4*)&Wco[pbase];

    // ---- cooperative fill of the LDS weight table (864 elements) ----
    // Wc[(g*64+co)*54 + ci*18 + dt*9 + kh*3 + kw]
    for (int fi = tid; fi < 864; fi += 256) {
        int cl2 = fi / 216;            // 216 = 4 gates * 54
        int r1  = fi - cl2 * 216;
        int g2  = r1 / 54;
        int r2  = r1 - g2 * 54;
        int ci  = r2 / 18;
        int r3  = r2 - ci * 18;
        int kh  = r3 / 6;
        int r4  = r3 - kh * 6;
        int dt  = r4 / 3;
        int kw  = r4 - dt * 3;
        wl[((cl2 * 4 + g2) * 9 + ci * 3 + kh) * 8 + dt * 3 + kw] =
            Wc[(size_t)(g2 * 64 + co0 + cl2) * 54 + ci * 18 + dt * 9 + kh * 3 + kw];
    }
    // biases for this wave's cout, all 4 gates -> SGPRs
    float bg0 = sgprf(bc[0 * 64 + co]);
    float bg1 = sgprf(bc[1 * 64 + co]);
    float bg2 = sgprf(bc[2 * 64 + co]);
    float bg3 = sgprf(bc[3 * 64 + co]);

    // ---- staging precompute: 5 chunks of 256 covering 3x6x66 halo tile ----
    const float* __restrict__ Xb = X + (size_t)b * (3 * TT * HW);
    int soff[5];
    int goff[5];
    int svmask = 0;
    #pragma unroll
    for (int k = 0; k < 5; ++k) {
        int idx  = tid + k * 256;
        bool inr = (idx < NSTG);
        int idc  = inr ? idx : 0;
        int ci   = idc / 396;              // 6*66
        int rem  = idc - ci * 396;
        int y    = rem / 66;
        int x    = rem - y * 66;
        int gh   = h0 + y - 1;
        int gw   = x - 1;
        bool v   = inr && (gh >= 0) && (gh < 64) && (gw >= 0) && (gw < 64);
        int ghc  = gh < 0 ? 0 : (gh > 63 ? 63 : gh);
        int gwc  = gw < 0 ? 0 : (gw > 63 ? 63 : gw);
        soff[k]  = inr ? (ci * LPLANE + y * LROW + x) : (LROW - 1); // dummy pad slot
        goff[k]  = ci * (TT * HW) + ghc * 64 + gwc;                 // plane 0
        svmask  |= (v ? 1 : 0) << k;
    }

    // prologue: stage plane t=0 into buffer 0
    #pragma unroll
    for (int k = 0; k < 5; ++k) {
        float v = ((svmask >> k) & 1) ? Xb[goff[k]] : 0.0f;
        sx[soff[k]] = v;
        goff[k] += HW;                       // -> plane 1
    }

    // output: this thread's 4 pixels are contiguous -> float4 stores
    float* __restrict__ outw =
        out + (size_t)(b * 64 + co) * (TT * HW) + (h0 + r) * 64 + c0;
    int ooff = 0;

    // nv = dt0 sums of current plane (becomes next step's carry); C = cell state
    float nv[4][4];
    #pragma unroll
    for (int g2 = 0; g2 < 4; ++g2)
        #pragma unroll
        for (int j = 0; j < 4; ++j) nv[g2][j] = 0.0f;
    float C0 = 0.f, C1 = 0.f, C2 = 0.f, C3 = 0.f;

    __syncthreads();   // plane 0 staged + weight table filled

    for (int t = 0; t < TT; ++t) {
        // never-taken uniform MayDef on wl: keeps LICM from hoisting the
        // weight loads into ~400 registers. grid.x==16 -> never executes.
        if (blockIdx.x == 0xFFFFFFFFu) wl[tid] = 0.0f;

        const float* __restrict__ sxb = &sx[(t & 1) * SXSZ];

        // s init = bias + carry (dt0 taps of plane t-1); reset n accumulators
        float sv[4][4];
        #pragma unroll
        for (int j = 0; j < 4; ++j) {
            sv[0][j] = bg0 + nv[0][j];  nv[0][j] = 0.f;
            sv[1][j] = bg1 + nv[1][j];  nv[1][j] = 0.f;
            sv[2][j] = bg2 + nv[2][j];  nv[2][j] = 0.f;
            sv[3][j] = bg3 + nv[3][j];  nv[3][j] = 0.f;
        }

        // prefetch next plane's staging values (VMEM overlaps FMAs)
        float stv[5];
        if (t < TT - 1) {                    // uniform branch
            #pragma unroll
            for (int k = 0; k < 5; ++k) {
                stv[k] = ((svmask >> k) & 1) ? Xb[goff[k]] : 0.0f;
                goff[k] += HW;
            }
        }

        // conv: all 4 gates, this wave's cout; window shared across gates
        #pragma unroll
        for (int ci = 0; ci < 3; ++ci)
            #pragma unroll
            for (int kh = 0; kh < 3; ++kh) {
                // window row: 6 floats (b128 + b64, 2-way banked = free)
                const float* rowp = &sxb[ci * LPLANE + (r + kh) * LROW + c0];
                float4 lo = *(const float4*)rowp;
                float2 hi = *(const float2*)(rowp + 4);
                const float w0 = lo.x, w1 = lo.y, w2 = lo.z;
                const float w3 = lo.w, w4 = hi.x, w5 = hi.y;

                #pragma unroll
                for (int g2 = 0; g2 < 4; ++g2) {
                    // uniform-address b128 broadcasts; q0={p0,p1,p2,c0}, q1={c1,c2,pad,pad}
                    const int wb = ((cl * 4 + g2) * 9 + ci * 3 + kh) * 8;
                    float4 q0 = *(const float4*)&wl[wb];
                    float4 q1 = *(const float4*)&wl[wb + 4];

                    sv[g2][0] += q0.w * w0;  sv[g2][1] += q0.w * w1;
                    sv[g2][2] += q0.w * w2;  sv[g2][3] += q0.w * w3;
                    sv[g2][0] += q1.x * w1;  sv[g2][1] += q1.x * w2;
                    sv[g2][2] += q1.x * w3;  sv[g2][3] += q1.x * w4;
                    sv[g2][0] += q1.y * w2;  sv[g2][1] += q1.y * w3;
                    sv[g2][2] += q1.y * w4;  sv[g2][3] += q1.y * w5;

                    nv[g2][0] += q0.x * w0;  nv[g2][1] += q0.x * w1;
                    nv[g2][2] += q0.x * w2;  nv[g2][3] += q0.x * w3;
                    nv[g2][0] += q0.y * w1;  nv[g2][1] += q0.y * w2;
                    nv[g2][2] += q0.y * w3;  nv[g2][3] += q0.y * w4;
                    nv[g2][0] += q0.z * w2;  nv[g2][1] += q0.z * w3;
                    nv[g2][2] += q0.z * w4;  nv[g2][3] += q0.z * w5;
                }
            }

        // commit staged plane t+1 (other buffer; readers of it finished at t-1)
        if (t < TT - 1) {                    // uniform branch
            float* __restrict__ sxn = &sx[((t + 1) & 1) * SXSZ];
            #pragma unroll
            for (int k = 0; k < 5; ++k) sxn[soff[k]] = stv[k];
        }

        // recurrence: fully thread-local (no exchange, no barrier needed)
        float o0, o1, o2, o3;
        {
            const float ig = fsigmoid(sv[0][0] + wciA[0] * C0);
            const float fg = fsigmoid(sv[1][0] + wcfA[0] * C0);
            const float Cn = fg * C0 + ig * ftanh(sv[2][0]);
            const float og = fsigmoid(sv[3][0] + wcoA[0] * Cn);
            o0 = og * ftanh(Cn);  C0 = Cn;
        }
        {
            const float ig = fsigmoid(sv[0][1] + wciA[1] * C1);
            const float fg = fsigmoid(sv[1][1] + wcfA[1] * C1);
            const float Cn = fg * C1 + ig * ftanh(sv[2][1]);
            const float og = fsigmoid(sv[3][1] + wcoA[1] * Cn);
            o1 = og * ftanh(Cn);  C1 = Cn;
        }
        {
            const float ig = fsigmoid(sv[0][2] + wciA[2] * C2);
            const float fg = fsigmoid(sv[1][2] + wcfA[2] * C2);
            const float Cn = fg * C2 + ig * ftanh(sv[2][2]);
            const float og = fsigmoid(sv[3][2] + wcoA[2] * Cn);
            o2 = og * ftanh(Cn);  C2 = Cn;
        }
        {
            const float ig = fsigmoid(sv[0][3] + wciA[3] * C3);
            const float fg = fsigmoid(sv[1][3] + wcfA[3] * C3);
            const float Cn = fg * C3 + ig * ftanh(sv[2][3]);
            const float og = fsigmoid(sv[3][3] + wcoA[3] * Cn);
            o3 = og * ftanh(Cn);  C3 = Cn;
        }
        *(float4*)&outw[ooff] = make_float4(o0, o1, o2, o3);
        ooff += HW;

        __syncthreads();   // staged plane t+1 visible; sx[t&1] reads done
    }
}

extern "C" void kernel_launch(void* const* d_in, const int* in_sizes, int n_in,
                              void* d_out, int out_size, void* d_ws, size_t ws_size,
                              hipStream_t stream) {
    const float* X   = (const float*)d_in[0];
    const float* Wc  = (const float*)d_in[1];
    const float* bc  = (const float*)d_in[2];
    const float* Wci = (const float*)d_in[3];
    const float* Wcf = (const float*)d_in[4];
    const float* Wco = (const float*)d_in[5];
    float* out = (float*)d_out;

    dim3 grid(16, 16, 4);   // row-tiles, cout-quads, batch
    convqrnn<<<grid, 256, 0, stream>>>(X, Wc, bc, Wci, Wcf, Wco, out);
}

// Round 8
// 1265.185 us; speedup vs baseline: 2.3510x; 2.3510x over previous
//
#include <hip/hip_runtime.h>

#define TT     32
#define HW     4096           // 64*64
#define LROW   68             // 66 cols + 2 pad -> rows 16B-aligned (b128 reads)
#define LPLANE (6 * LROW)     // 6 halo rows per cin = 408
#define SXSZ   (3 * LPLANE)   // 1224 floats per plane buffer
#define NSTG   (3 * 6 * 66)   // 1188 staged elements per plane

__device__ __forceinline__ float fsigmoid(float x) {
    return __builtin_amdgcn_rcpf(1.0f + __builtin_amdgcn_exp2f(x * -1.4426950408889634f));
}
__device__ __forceinline__ float ftanh(float x) {
    return 2.0f * __builtin_amdgcn_rcpf(1.0f + __builtin_amdgcn_exp2f(x * -2.8853900817779268f)) - 1.0f;
}
// force a wave-uniform float into an SGPR
__device__ __forceinline__ float sgprf(float v) {
    return __uint_as_float(__builtin_amdgcn_readfirstlane(__float_as_uint(v)));
}

// (256,2): the ONLY launch-bounds tier that has yielded >64 VGPRs cleanly
// (round 0: 112 VGPR no spill). (256,4) pins the allocator at 64 VGPR and
// spills the 32 conv accumulators to scratch (round 7: 11 GB scratch traffic).
__global__ __launch_bounds__(256, 2) void convqrnn(
    const float* __restrict__ X,    // (4,3,32,64,64)
    const float* __restrict__ Wc,   // (256,3,2,3,3)
    const float* __restrict__ bc,   // (256)
    const float* __restrict__ Wci,  // (64,64,64)
    const float* __restrict__ Wcf,
    const float* __restrict__ Wco,
    float* __restrict__ out)        // (4,64,32,64,64)
{
    __shared__ float sx[2 * SXSZ];   // double-buffered staged plane (9792 B)
    __shared__ float wl[1152];       // weights: ((cl*4+g)*9 + ci*3+kh)*8 + dt*3 + kw

    const int tid = threadIdx.x;
    const int h0  = blockIdx.x * 4;    // 16 row-tiles of height 4, full width
    const int co0 = blockIdx.y * 4;    // this block handles couts co0..co0+3
    const int b   = blockIdx.z;

    // wave cl owns cout co0+cl, ALL 4 gates, for its lane's 4-col strip
    const int cl = tid >> 6;           // wave-uniform cout-local
    const int co = co0 + cl;
    const int l  = tid & 63;
    const int r  = l >> 4;             // 0..3 tile row
    const int c0 = (l & 15) * 4;       // col base (0,4,...,60)

    // peephole params for this thread's 4 pixels: contiguous -> float4
    const int pbase = co * HW + (h0 + r) * 64 + c0;
    float wciA[4], wcfA[4], wcoA[4];
    *(float4*)wciA = *(const float4*)&Wci[pbase];
    *(float4*)wcfA = *(const float4*)&Wcf[pbase];
    *(float4*)wcoA = *(const float4*)&Wco[pbase];

    // ---- cooperative fill of the LDS weight table (864 elements) ----
    // Wc[(g*64+co)*54 + ci*18 + dt*9 + kh*3 + kw]
    for (int fi = tid; fi < 864; fi += 256) {
        int cl2 = fi / 216;            // 216 = 4 gates * 54
        int r1  = fi - cl2 * 216;
        int g2  = r1 / 54;
        int r2  = r1 - g2 * 54;
        int ci  = r2 / 18;
        int r3  = r2 - ci * 18;
        int kh  = r3 / 6;
        int r4  = r3 - kh * 6;
        int dt  = r4 / 3;
        int kw  = r4 - dt * 3;
        wl[((cl2 * 4 + g2) * 9 + ci * 3 + kh) * 8 + dt * 3 + kw] =
            Wc[(size_t)(g2 * 64 + co0 + cl2) * 54 + ci * 18 + dt * 9 + kh * 3 + kw];
    }
    // biases for this wave's cout, all 4 gates -> SGPRs
    float bg0 = sgprf(bc[0 * 64 + co]);
    float bg1 = sgprf(bc[1 * 64 + co]);
    float bg2 = sgprf(bc[2 * 64 + co]);
    float bg3 = sgprf(bc[3 * 64 + co]);

    // ---- staging precompute: 5 chunks of 256 covering 3x6x66 halo tile ----
    const float* __restrict__ Xb = X + (size_t)b * (3 * TT * HW);
    int soff[5];
    int goff[5];
    int svmask = 0;
    #pragma unroll
    for (int k = 0; k < 5; ++k) {
        int idx  = tid + k * 256;
        bool inr = (idx < NSTG);
        int idc  = inr ? idx : 0;
        int ci   = idc / 396;              // 6*66
        int rem  = idc - ci * 396;
        int y    = rem / 66;
        int x    = rem - y * 66;
        int gh   = h0 + y - 1;
        int gw   = x - 1;
        bool v   = inr && (gh >= 0) && (gh < 64) && (gw >= 0) && (gw < 64);
        int ghc  = gh < 0 ? 0 : (gh > 63 ? 63 : gh);
        int gwc  = gw < 0 ? 0 : (gw > 63 ? 63 : gw);
        soff[k]  = inr ? (ci * LPLANE + y * LROW + x) : (LROW - 1); // dummy pad slot
        goff[k]  = ci * (TT * HW) + ghc * 64 + gwc;                 // plane 0
        svmask  |= (v ? 1 : 0) << k;
    }

    // prologue: stage plane t=0 into buffer 0
    #pragma unroll
    for (int k = 0; k < 5; ++k) {
        float v = ((svmask >> k) & 1) ? Xb[goff[k]] : 0.0f;
        sx[soff[k]] = v;
        goff[k] += HW;                       // -> plane 1
    }

    // output: this thread's 4 pixels are contiguous -> float4 stores
    float* __restrict__ outw =
        out + (size_t)(b * 64 + co) * (TT * HW) + (h0 + r) * 64 + c0;
    int ooff = 0;

    // nv = dt0 sums of current plane (becomes next step's carry); C = cell state
    float nv[4][4];
    #pragma unroll
    for (int g2 = 0; g2 < 4; ++g2)
        #pragma unroll
        for (int j = 0; j < 4; ++j) nv[g2][j] = 0.0f;
    float C0 = 0.f, C1 = 0.f, C2 = 0.f, C3 = 0.f;

    __syncthreads();   // plane 0 staged + weight table filled

    for (int t = 0; t < TT; ++t) {
        // never-taken uniform MayDef on wl: keeps LICM from hoisting the
        // weight loads into ~400 registers. grid.x==16 -> never executes.
        if (blockIdx.x == 0xFFFFFFFFu) wl[tid] = 0.0f;

        const float* __restrict__ sxb = &sx[(t & 1) * SXSZ];

        // s init = bias + carry (dt0 taps of plane t-1); reset n accumulators
        float sv[4][4];
        #pragma unroll
        for (int j = 0; j < 4; ++j) {
            sv[0][j] = bg0 + nv[0][j];  nv[0][j] = 0.f;
            sv[1][j] = bg1 + nv[1][j];  nv[1][j] = 0.f;
            sv[2][j] = bg2 + nv[2][j];  nv[2][j] = 0.f;
            sv[3][j] = bg3 + nv[3][j];  nv[3][j] = 0.f;
        }

        // prefetch next plane's staging values (VMEM overlaps FMAs)
        float stv[5];
        if (t < TT - 1) {                    // uniform branch
            #pragma unroll
            for (int k = 0; k < 5; ++k) {
                stv[k] = ((svmask >> k) & 1) ? Xb[goff[k]] : 0.0f;
                goff[k] += HW;
            }
        }

        // conv: all 4 gates, this wave's cout; window shared across gates
        #pragma unroll
        for (int ci = 0; ci < 3; ++ci)
            #pragma unroll
            for (int kh = 0; kh < 3; ++kh) {
                // window row: 6 floats (b128 + b64, 2-way banked = free)
                const float* rowp = &sxb[ci * LPLANE + (r + kh) * LROW + c0];
                float4 lo = *(const float4*)rowp;
                float2 hi = *(const float2*)(rowp + 4);
                const float w0 = lo.x, w1 = lo.y, w2 = lo.z;
                const float w3 = lo.w, w4 = hi.x, w5 = hi.y;

                #pragma unroll
                for (int g2 = 0; g2 < 4; ++g2) {
                    // uniform-address b128 broadcasts; q0={p0,p1,p2,c0}, q1={c1,c2,pad,pad}
                    const int wb = ((cl * 4 + g2) * 9 + ci * 3 + kh) * 8;
                    float4 q0 = *(const float4*)&wl[wb];
                    float4 q1 = *(const float4*)&wl[wb + 4];

                    sv[g2][0] += q0.w * w0;  sv[g2][1] += q0.w * w1;
                    sv[g2][2] += q0.w * w2;  sv[g2][3] += q0.w * w3;
                    sv[g2][0] += q1.x * w1;  sv[g2][1] += q1.x * w2;
                    sv[g2][2] += q1.x * w3;  sv[g2][3] += q1.x * w4;
                    sv[g2][0] += q1.y * w2;  sv[g2][1] += q1.y * w3;
                    sv[g2][2] += q1.y * w4;  sv[g2][3] += q1.y * w5;

                    nv[g2][0] += q0.x * w0;  nv[g2][1] += q0.x * w1;
                    nv[g2][2] += q0.x * w2;  nv[g2][3] += q0.x * w3;
                    nv[g2][0] += q0.y * w1;  nv[g2][1] += q0.y * w2;
                    nv[g2][2] += q0.y * w3;  nv[g2][3] += q0.y * w4;
                    nv[g2][0] += q0.z * w2;  nv[g2][1] += q0.z * w3;
                    nv[g2][2] += q0.z * w4;  nv[g2][3] += q0.z * w5;
                }
            }

        // commit staged plane t+1 (other buffer; readers of it finished at t-1)
        if (t < TT - 1) {                    // uniform branch
            float* __restrict__ sxn = &sx[((t + 1) & 1) * SXSZ];
            #pragma unroll
            for (int k = 0; k < 5; ++k) sxn[soff[k]] = stv[k];
        }

        // recurrence: fully thread-local (no exchange, no barrier needed)
        float o0, o1, o2, o3;
        {
            const float ig = fsigmoid(sv[0][0] + wciA[0] * C0);
            const float fg = fsigmoid(sv[1][0] + wcfA[0] * C0);
            const float Cn = fg * C0 + ig * ftanh(sv[2][0]);
            const float og = fsigmoid(sv[3][0] + wcoA[0] * Cn);
            o0 = og * ftanh(Cn);  C0 = Cn;
        }
        {
            const float ig = fsigmoid(sv[0][1] + wciA[1] * C1);
            const float fg = fsigmoid(sv[1][1] + wcfA[1] * C1);
            const float Cn = fg * C1 + ig * ftanh(sv[2][1]);
            const float og = fsigmoid(sv[3][1] + wcoA[1] * Cn);
            o1 = og * ftanh(Cn);  C1 = Cn;
        }
        {
            const float ig = fsigmoid(sv[0][2] + wciA[2] * C2);
            const float fg = fsigmoid(sv[1][2] + wcfA[2] * C2);
            const float Cn = fg * C2 + ig * ftanh(sv[2][2]);
            const float og = fsigmoid(sv[3][2] + wcoA[2] * Cn);
            o2 = og * ftanh(Cn);  C2 = Cn;
        }
        {
            const float ig = fsigmoid(sv[0][3] + wciA[3] * C3);
            const float fg = fsigmoid(sv[1][3] + wcfA[3] * C3);
            const float Cn = fg * C3 + ig * ftanh(sv[2][3]);
            const float og = fsigmoid(sv[3][3] + wcoA[3] * Cn);
            o3 = og * ftanh(Cn);  C3 = Cn;
        }
        *(float4*)&outw[ooff] = make_float4(o0, o1, o2, o3);
        ooff += HW;

        __syncthreads();   // staged plane t+1 visible; sx[t&1] reads done
    }
}

extern "C" void kernel_launch(void* const* d_in, const int* in_sizes, int n_in,
                              void* d_out, int out_size, void* d_ws, size_t ws_size,
                              hipStream_t stream) {
    const float* X   = (const float*)d_in[0];
    const float* Wc  = (const float*)d_in[1];
    const float* bc  = (const float*)d_in[2];
    const float* Wci = (const float*)d_in[3];
    const float* Wcf = (const float*)d_in[4];
    const float* Wco = (const float*)d_in[5];
    float* out = (float*)d_out;

    dim3 grid(16, 16, 4);   // row-tiles, cout-quads, batch
    convqrnn<<<grid, 256, 0, stream>>>(X, Wc, bc, Wci, Wcf, Wco, out);
}